// Round 8
// baseline (1320.352 us; speedup 1.0000x reference)
//
#include <hip/hip_runtime.h>

#define N_NODES 100000
#define N_EDGES 1600000
#define HDIM    64
#define NLAYERS 5
#define NGRAPH  128
#define NOUT    10
#define BN_EPS  1e-5f
#define NBUCK   196          // ceil(N_NODES / 512)
#define EPB     8192         // edges per binfill block
#define NTILES  (N_NODES / 16)   // 6250 exact

typedef __attribute__((ext_vector_type(8))) short bf16x8;
typedef __attribute__((ext_vector_type(4))) float f32x4;

static __device__ __forceinline__ unsigned short f2bf(float f) {
    unsigned u = __float_as_uint(f);
    unsigned r = (u + 0x7FFFu + ((u >> 16) & 1u)) >> 16;
    return (unsigned short)r;
}
static __device__ __forceinline__ float bf2f(unsigned short h) {
    return __uint_as_float(((unsigned)h) << 16);
}

// ---------------- CSR build ----------------

__global__ __launch_bounds__(256) void k_hist(const int* __restrict__ dst, int* __restrict__ counts) {
    int e = blockIdx.x * 256 + threadIdx.x;
    if (e < N_EDGES) atomicAdd(&counts[dst[e]], 1);
}

__global__ __launch_bounds__(256) void k_scan_bt(const int* __restrict__ counts, int* __restrict__ bsums) {
    __shared__ int sm[256];
    int t = threadIdx.x;
    int base = blockIdx.x * 1024 + t * 4;
    int s = 0;
#pragma unroll
    for (int k = 0; k < 4; ++k) { int i = base + k; s += (i < N_NODES) ? counts[i] : 0; }
    sm[t] = s; __syncthreads();
    for (int o = 128; o > 0; o >>= 1) { if (t < o) sm[t] += sm[t + o]; __syncthreads(); }
    if (t == 0) bsums[blockIdx.x] = sm[0];
}

__global__ void k_scan_tot(int* bsums, int nblk, int* offsets) {
    if (threadIdx.x == 0 && blockIdx.x == 0) {
        int run = 0;
        for (int i = 0; i < nblk; ++i) { int v = bsums[i]; bsums[i] = run; run += v; }
        offsets[N_NODES] = N_EDGES;
    }
}

__global__ __launch_bounds__(256) void k_scan_fin(const int* __restrict__ counts, const int* __restrict__ bsums,
                                                 int* __restrict__ offsets, int* __restrict__ cursor) {
    __shared__ int sm[256];
    int t = threadIdx.x;
    int base = blockIdx.x * 1024 + t * 4;
    int v[4]; int s = 0;
#pragma unroll
    for (int k = 0; k < 4; ++k) { int i = base + k; v[k] = (i < N_NODES) ? counts[i] : 0; s += v[k]; }
    sm[t] = s; __syncthreads();
    for (int o = 1; o < 256; o <<= 1) {
        int add = (t >= o) ? sm[t - o] : 0;
        __syncthreads();
        sm[t] += add;
        __syncthreads();
    }
    int run = bsums[blockIdx.x] + (sm[t] - s);
#pragma unroll
    for (int k = 0; k < 4; ++k) {
        int i = base + k;
        if (i < N_NODES) { offsets[i] = run; cursor[i] = run; run += v[k]; }
    }
}

__global__ void k_binit(const int* __restrict__ offs, int* __restrict__ bcursor) {
    int b = blockIdx.x * 256 + threadIdx.x;
    if (b < NBUCK) bcursor[b] = offs[b << 9];
}

__global__ __launch_bounds__(1024) void k_binfill(const int* __restrict__ src, const int* __restrict__ dst,
                                                  int* __restrict__ bcursor, unsigned* __restrict__ tmp) {
    __shared__ unsigned slots[EPB];
    __shared__ int cnt[NBUCK], lcur[NBUCK], gbase[NBUCK];
    __shared__ int lbase[NBUCK + 1];
    __shared__ int sscan[256];
    int t = threadIdx.x;
    int e0 = blockIdx.x * EPB;
    for (int i = t; i < NBUCK; i += 1024) { cnt[i] = 0; lcur[i] = 0; }
    __syncthreads();
    unsigned pk[8]; int bk[8];
#pragma unroll
    for (int k = 0; k < 8; ++k) {
        int e = e0 + k * 1024 + t;
        bk[k] = -1;
        if (e < N_EDGES) {
            int s = src[e], d = dst[e];
            int b = d >> 9;
            pk[k] = ((unsigned)(d & 511) << 17) | (unsigned)s;
            bk[k] = b;
            atomicAdd(&cnt[b], 1);
        }
    }
    __syncthreads();
    if (t < 256) sscan[t] = (t < NBUCK) ? cnt[t] : 0;
    __syncthreads();
    for (int o = 1; o < 256; o <<= 1) {
        int v = 0;
        if (t < 256 && t >= o) v = sscan[t - o];
        __syncthreads();
        if (t < 256) sscan[t] += v;
        __syncthreads();
    }
    if (t < NBUCK) {
        lbase[t] = sscan[t] - cnt[t];
        gbase[t] = atomicAdd(&bcursor[t], cnt[t]);
    }
    if (t == 0) lbase[NBUCK] = sscan[255];
    __syncthreads();
#pragma unroll
    for (int k = 0; k < 8; ++k) {
        if (bk[k] >= 0) {
            int pos = lbase[bk[k]] + atomicAdd(&lcur[bk[k]], 1);
            slots[pos] = pk[k];
        }
    }
    __syncthreads();
    int total = lbase[NBUCK];
    for (int i = t; i < total; i += 1024) {
        int lo = 0, hi = NBUCK - 1;
        while (lo < hi) { int mid = (lo + hi + 1) >> 1; if (lbase[mid] <= i) lo = mid; else hi = mid - 1; }
        tmp[gbase[lo] + (i - lbase[lo])] = slots[i];
    }
}

__global__ __launch_bounds__(1024) void k_localcsr(const unsigned* __restrict__ tmp, const int* __restrict__ offs,
                                                   int* __restrict__ cursor, int* __restrict__ csr) {
    int b = blockIdx.x;
    int nlo = b << 9;
    int nhi = nlo + 512; if (nhi > N_NODES) nhi = N_NODES;
    int base = offs[nlo], end = offs[nhi];
    for (int i = base + (int)threadIdx.x; i < end; i += 1024) {
        unsigned pk = tmp[i];
        int node = nlo + (int)(pk >> 17);
        int p = atomicAdd(&cursor[node], 1);
        csr[p] = (int)(pk & 0x1FFFFu);
    }
}

// ---------------- weight pre-pack: f32 -> bf16 hi/lo frag order ----------------
// frag slot formula (shared by A and B fills): k = 32*ks + 8*(lane>>4) + j, n/col = 16*nt + (lane&15)
__global__ __launch_bounds__(256) void k_wcvt(const float* __restrict__ cW1, const float* __restrict__ cW2,
                                              unsigned short* __restrict__ whi, unsigned short* __restrict__ wlo) {
    int tid = blockIdx.x * 256 + threadIdx.x;   // 5*2*2*4*64 = 5120
    if (tid >= 5120) return;
    int lane = tid & 63;
    int r = tid >> 6;        // ((layer*2+gemm)*2+ks)*4+nt
    int nt = r & 3;
    int ks = (r >> 2) & 1;
    int gemm = (r >> 3) & 1;
    int layer = r >> 4;
    const float* W = (gemm ? cW2 : cW1) + (size_t)layer * 4096;
    size_t ob = ((size_t)r * 64 + lane) * 8;
#pragma unroll
    for (int j = 0; j < 8; ++j) {
        float w = W[(32 * ks + 8 * (lane >> 4) + j) * 64 + 16 * nt + (lane & 15)];
        unsigned short h = f2bf(w);
        whi[ob + j] = h;
        wlo[ob + j] = f2bf(w - bf2f(h));
    }
}

// ---------------- per-layer kernels ----------------

static __device__ __forceinline__ void bn_coeffs(const float* stats, const float* gam, const float* bet,
                                                 int j0, float4& sc, float4& sh) {
    const float invN = 1.0f / (float)N_NODES;
    float m, v, s;
    m = stats[j0+0]*invN; v = stats[64+j0+0]*invN - m*m; s = gam[j0+0]*rsqrtf(v+BN_EPS); sc.x = s; sh.x = bet[j0+0]-m*s;
    m = stats[j0+1]*invN; v = stats[64+j0+1]*invN - m*m; s = gam[j0+1]*rsqrtf(v+BN_EPS); sc.y = s; sh.y = bet[j0+1]-m*s;
    m = stats[j0+2]*invN; v = stats[64+j0+2]*invN - m*m; s = gam[j0+2]*rsqrtf(v+BN_EPS); sc.z = s; sh.z = bet[j0+2]-m*s;
    m = stats[j0+3]*invN; v = stats[64+j0+3]*invN - m*m; s = gam[j0+3]*rsqrtf(v+BN_EPS); sc.w = s; sh.w = bet[j0+3]-m*s;
}

static __device__ __forceinline__ float4 bn_apply(float4 v, const float4& sc, const float4& sh) {
    v.x = fmaxf(fmaf(v.x, sc.x, sh.x), 0.f);
    v.y = fmaxf(fmaf(v.y, sc.y, sh.y), 0.f);
    v.z = fmaxf(fmaf(v.z, sc.z, sh.z), 0.f);
    v.w = fmaxf(fmaf(v.w, sc.w, sh.w), 0.f);
    return v;
}

// 16 lanes per node, float4 per lane. GIN input fused: starts from own row
// (BN'd for layers>0), adds all neighbors -> writes x + sum_neighbors.
template <bool APPLY>
__global__ __launch_bounds__(256) void k_agg(const float4* __restrict__ x4, const int* __restrict__ offsets,
                                             const int* __restrict__ csr, float4* __restrict__ agg4,
                                             const float* __restrict__ stats, const float* __restrict__ gam,
                                             const float* __restrict__ bet) {
    int tid = blockIdx.x * 256 + threadIdx.x;
    int n = tid >> 4, q = tid & 15;
    if (n >= N_NODES) return;
    float4 sc, sh;
    if (APPLY) bn_coeffs(stats, gam, bet, q * 4, sc, sh);
    int beg = offsets[n], end = offsets[n + 1];
    float4 a0 = x4[(size_t)n * 16 + q];          // self term (eps=0)
    if (APPLY) a0 = bn_apply(a0, sc, sh);
    float4 a1 = make_float4(0.f, 0.f, 0.f, 0.f);
    int e = beg;
    for (; e + 1 < end; e += 2) {
        int s0 = csr[e], s1 = csr[e + 1];
        float4 v0 = x4[(size_t)s0 * 16 + q];
        float4 v1 = x4[(size_t)s1 * 16 + q];
        if (APPLY) { v0 = bn_apply(v0, sc, sh); v1 = bn_apply(v1, sc, sh); }
        a0.x += v0.x; a0.y += v0.y; a0.z += v0.z; a0.w += v0.w;
        a1.x += v1.x; a1.y += v1.y; a1.z += v1.z; a1.w += v1.w;
    }
    if (e < end) {
        int s0 = csr[e];
        float4 v0 = x4[(size_t)s0 * 16 + q];
        if (APPLY) v0 = bn_apply(v0, sc, sh);
        a0.x += v0.x; a0.y += v0.y; a0.z += v0.z; a0.w += v0.w;
    }
    a0.x += a1.x; a0.y += a1.y; a0.z += a1.z; a0.w += a1.w;
    agg4[(size_t)n * 16 + q] = a0;
}

// MFMA MLP, 1 tile/wave, in-place over agg. All W1 frags preloaded into
// registers WITH the input loads (20 independent loads in flight -> one
// vmcnt wait). W2 frags loaded after GEMM1 (latency hides under GEMM1 +
// LDS transpose). sched_barrier keeps the two phases separate so peak
// VGPR stays under the (256,3) cap.
// C/D layout: col = lane&15, row = (lane>>4)*4 + reg.
// A/B slot fill: k = 32*ks + 8*(lane>>4) + j (consistent A<->B).
__global__ __launch_bounds__(256, 3) void k_mlp5(float* __restrict__ aggh2,
                                              const unsigned short* __restrict__ w1hi, const unsigned short* __restrict__ w1lo,
                                              const unsigned short* __restrict__ w2hi, const unsigned short* __restrict__ w2lo,
                                              const float* __restrict__ b1, const float* __restrict__ b2,
                                              float* __restrict__ statsOut) {
    __shared__ float h1s[4][16 * 68];
    int t = threadIdx.x;
    int lane = t & 63;
    int wv = t >> 6;
    int lr = lane & 15;
    int lg = lane >> 4;
    int tile = blockIdx.x * 4 + wv;
    if (tile >= NTILES) return;               // no barriers below: safe
    float* myh1 = &h1s[wv][0];

    // ---- phase 1: W1 frags + input, all issued together ----
    bf16x8 w1h[8], w1l[8];                    // [ks*4+nt]
#pragma unroll
    for (int i = 0; i < 8; ++i) {
        w1h[i] = *(const bf16x8*)(w1hi + ((size_t)(i * 64 + lane)) * 8);
        w1l[i] = *(const bf16x8*)(w1lo + ((size_t)(i * 64 + lane)) * 8);
    }
    const float4* base = (const float4*)(aggh2 + (size_t)(tile * 16 + lr) * 64);
    float4 L[4];
    L[0] = base[2 * lg];     L[1] = base[2 * lg + 1];
    L[2] = base[8 + 2 * lg]; L[3] = base[8 + 2 * lg + 1];
    float bias1[4], bias2[4];
#pragma unroll
    for (int nt = 0; nt < 4; ++nt) { bias1[nt] = b1[16 * nt + lr]; bias2[nt] = b2[16 * nt + lr]; }

    bf16x8 Ah[2], Al[2];
#pragma unroll
    for (int ks = 0; ks < 2; ++ks) {
        float in[8] = {L[2*ks].x, L[2*ks].y, L[2*ks].z, L[2*ks].w,
                       L[2*ks+1].x, L[2*ks+1].y, L[2*ks+1].z, L[2*ks+1].w};
#pragma unroll
        for (int j = 0; j < 8; ++j) {
            unsigned short h = f2bf(in[j]);
            Ah[ks][j] = (short)h;
            Al[ks][j] = (short)f2bf(in[j] - bf2f(h));
        }
    }
#pragma unroll
    for (int nt = 0; nt < 4; ++nt) {
        f32x4 c = {bias1[nt], bias1[nt], bias1[nt], bias1[nt]};
#pragma unroll
        for (int ks = 0; ks < 2; ++ks) {
            c = __builtin_amdgcn_mfma_f32_16x16x32_bf16(Ah[ks], w1h[ks * 4 + nt], c, 0, 0, 0);
            c = __builtin_amdgcn_mfma_f32_16x16x32_bf16(Ah[ks], w1l[ks * 4 + nt], c, 0, 0, 0);
            c = __builtin_amdgcn_mfma_f32_16x16x32_bf16(Al[ks], w1h[ks * 4 + nt], c, 0, 0, 0);
        }
        // relu + stage h1 (row = 4*lg + r, col = 16*nt + lr), stride 68
#pragma unroll
        for (int r = 0; r < 4; ++r)
            myh1[(4 * lg + r) * 68 + 16 * nt + lr] = fmaxf(c[r], 0.f);
    }

    __builtin_amdgcn_sched_barrier(0);        // keep W2 loads out of phase 1

    // ---- phase 2: W2 frags (latency hides under LDS transpose) ----
    bf16x8 w2h[8], w2l[8];
#pragma unroll
    for (int i = 0; i < 8; ++i) {
        w2h[i] = *(const bf16x8*)(w2hi + ((size_t)(i * 64 + lane)) * 8);
        w2l[i] = *(const bf16x8*)(w2lo + ((size_t)(i * 64 + lane)) * 8);
    }
    bf16x8 A2h[2], A2l[2];
#pragma unroll
    for (int ks = 0; ks < 2; ++ks) {
        const float* hr = &myh1[lr * 68 + 32 * ks + 8 * lg];
        float4 h0 = *(const float4*)hr;
        float4 h1v = *(const float4*)(hr + 4);
        float hv[8] = {h0.x, h0.y, h0.z, h0.w, h1v.x, h1v.y, h1v.z, h1v.w};
#pragma unroll
        for (int j = 0; j < 8; ++j) {
            unsigned short hh = f2bf(hv[j]);
            A2h[ks][j] = (short)hh;
            A2l[ks][j] = (short)f2bf(hv[j] - bf2f(hh));
        }
    }
    float st_s[4], st_q[4];
    int nodeb = tile * 16;
#pragma unroll
    for (int nt = 0; nt < 4; ++nt) {
        f32x4 c = {bias2[nt], bias2[nt], bias2[nt], bias2[nt]};
#pragma unroll
        for (int ks = 0; ks < 2; ++ks) {
            c = __builtin_amdgcn_mfma_f32_16x16x32_bf16(A2h[ks], w2h[ks * 4 + nt], c, 0, 0, 0);
            c = __builtin_amdgcn_mfma_f32_16x16x32_bf16(A2h[ks], w2l[ks * 4 + nt], c, 0, 0, 0);
            c = __builtin_amdgcn_mfma_f32_16x16x32_bf16(A2l[ks], w2h[ks * 4 + nt], c, 0, 0, 0);
        }
        float s = 0.f, q = 0.f;
#pragma unroll
        for (int r = 0; r < 4; ++r) {
            float v = c[r];
            aggh2[(size_t)(nodeb + 4 * lg + r) * 64 + 16 * nt + lr] = v;
            s += v; q += v * v;
        }
        st_s[nt] = s; st_q[nt] = q;
    }

    // stats: lanes {l, l+16, l+32, l+48} hold same output column
#pragma unroll
    for (int nt = 0; nt < 4; ++nt) {
        float s = st_s[nt], q = st_q[nt];
        s += __shfl_xor(s, 16); q += __shfl_xor(q, 16);
        s += __shfl_xor(s, 32); q += __shfl_xor(q, 32);
        if (lg == 0) {
            atomicAdd(&statsOut[16 * nt + lr], s);
            atomicAdd(&statsOut[64 + 16 * nt + lr], q);
        }
    }
}

// ---------------- pooling + head ----------------

__global__ void k_bounds(const int* __restrict__ b, int* __restrict__ bounds) {
    int g = threadIdx.x;
    if (g > NGRAPH) return;
    int lo = 0, hi = N_NODES;
    while (lo < hi) { int mid = (lo + hi) >> 1; if (b[mid] < g) lo = mid + 1; else hi = mid; }
    bounds[g] = lo;
}

__global__ __launch_bounds__(256) void k_pool(const float4* __restrict__ x4, const int* __restrict__ bounds,
                                              float4* __restrict__ pooled4, const float* __restrict__ stats,
                                              const float* __restrict__ gam, const float* __restrict__ bet) {
    int g = blockIdx.x;
    int beg = bounds[g], end = bounds[g + 1];
    int t = threadIdx.x;
    int q = t & 15;
    int w = t >> 4;
    float4 sc, sh;
    bn_coeffs(stats, gam, bet, q * 4, sc, sh);
    float4 a = make_float4(0.f, 0.f, 0.f, 0.f);
    for (int n = beg + w; n < end; n += 16) {
        float4 v = bn_apply(x4[(size_t)n * 16 + q], sc, sh);
        a.x += v.x; a.y += v.y; a.z += v.z; a.w += v.w;
    }
    __shared__ float4 sm[16][16];
    sm[w][q] = a; __syncthreads();
    for (int o = 8; o > 0; o >>= 1) {
        if (w < o) {
            float4 u = sm[w + o][q];
            sm[w][q].x += u.x; sm[w][q].y += u.y; sm[w][q].z += u.z; sm[w][q].w += u.w;
        }
        __syncthreads();
    }
    if (w == 0) {
        float inv = (end > beg) ? 1.0f / (float)(end - beg) : 0.0f;
        float4 r = sm[0][q];
        r.x *= inv; r.y *= inv; r.z *= inv; r.w *= inv;
        pooled4[g * 16 + q] = r;
    }
}

__global__ __launch_bounds__(128) void k_head(const float* __restrict__ pooled,
                                              const float* __restrict__ W1, const float* __restrict__ b1,
                                              const float* __restrict__ W2, const float* __restrict__ b2,
                                              float* __restrict__ out) {
    __shared__ float w1s[64 * 64];
    __shared__ float w2s[64 * NOUT];
    int t = threadIdx.x;
    for (int i = t; i < 64 * 64; i += 128) w1s[i] = W1[i];
    for (int i = t; i < 64 * NOUT; i += 128) w2s[i] = W2[i];
    __syncthreads();
    int g = t;
    float pr[64];
#pragma unroll
    for (int k = 0; k < 64; ++k) pr[k] = pooled[g * 64 + k];
    float acc[NOUT];
#pragma unroll
    for (int o = 0; o < NOUT; ++o) acc[o] = b2[o];
    for (int j = 0; j < 64; ++j) {
        float h = b1[j];
#pragma unroll
        for (int k = 0; k < 64; ++k) h = fmaf(pr[k], w1s[k * 64 + j], h);
        h = fmaxf(h, 0.f);
#pragma unroll
        for (int o = 0; o < NOUT; ++o) acc[o] = fmaf(h, w2s[j * NOUT + o], acc[o]);
    }
#pragma unroll
    for (int o = 0; o < NOUT; ++o) out[g * NOUT + o] = acc[o];
}

// ---------------- launch ----------------

extern "C" void kernel_launch(void* const* d_in, const int* in_sizes, int n_in,
                              void* d_out, int out_size, void* d_ws, size_t ws_size,
                              hipStream_t stream) {
    const float* x0  = (const float*)d_in[0];
    const int*   ei  = (const int*)d_in[1];
    const int*   b   = (const int*)d_in[2];
    const float* cW1 = (const float*)d_in[3];
    const float* cb1 = (const float*)d_in[4];
    const float* cW2 = (const float*)d_in[5];
    const float* cb2 = (const float*)d_in[6];
    const float* gam = (const float*)d_in[7];
    const float* bet = (const float*)d_in[8];
    const float* hW1 = (const float*)d_in[9];
    const float* hb1 = (const float*)d_in[10];
    const float* hW2 = (const float*)d_in[11];
    const float* hb2 = (const float*)d_in[12];
    float* out = (float*)d_out;

    char* ws = (char*)d_ws;
    size_t off = 0;
    auto alloc = [&](size_t bytes) { void* p = ws + off; off += (bytes + 255) & ~(size_t)255; return p; };
    float* bufA   = (float*)alloc((size_t)N_NODES * 64 * sizeof(float));
    float* bufB   = (float*)alloc((size_t)N_NODES * 64 * sizeof(float));
    int*   csr    = (int*)alloc((size_t)N_EDGES * sizeof(int));
    int*   counts = (int*)alloc((size_t)(N_NODES + 1) * sizeof(int));
    int*   offs   = (int*)alloc((size_t)(N_NODES + 1) * sizeof(int));
    int*   cursor = (int*)alloc((size_t)(N_NODES + 1) * sizeof(int));
    int*   bsums  = (int*)alloc(256 * sizeof(int));
    int*   bcursor= (int*)alloc(256 * sizeof(int));
    float* stats  = (float*)alloc(NLAYERS * 128 * sizeof(float));
    float* pooled = (float*)alloc(NGRAPH * 64 * sizeof(float));
    int*   bounds = (int*)alloc((NGRAPH + 1) * sizeof(int));
    unsigned short* whi = (unsigned short*)alloc(5 * 2 * 4096 * sizeof(unsigned short));
    unsigned short* wlo = (unsigned short*)alloc(5 * 2 * 4096 * sizeof(unsigned short));
    unsigned* tmp = (unsigned*)bufB;   // alias: bufB unused until layer 1

    const int* src = ei;
    const int* dst = ei + N_EDGES;

    hipMemsetAsync(counts, 0, (N_NODES + 1) * sizeof(int), stream);
    hipMemsetAsync(stats, 0, NLAYERS * 128 * sizeof(float), stream);

    const int EB = (N_EDGES + 255) / 256;
    const int SB = (N_NODES + 1023) / 1024;
    const int FB = (N_EDGES + EPB - 1) / EPB;
    k_hist<<<EB, 256, 0, stream>>>(dst, counts);
    k_scan_bt<<<SB, 256, 0, stream>>>(counts, bsums);
    k_scan_tot<<<1, 1, 0, stream>>>(bsums, SB, offs);
    k_scan_fin<<<SB, 256, 0, stream>>>(counts, bsums, offs, cursor);
    k_binit<<<1, 256, 0, stream>>>(offs, bcursor);
    k_binfill<<<FB, 1024, 0, stream>>>(src, dst, bcursor, tmp);
    k_localcsr<<<NBUCK, 1024, 0, stream>>>(tmp, offs, cursor, csr);
    k_bounds<<<1, NGRAPH + 1, 0, stream>>>(b, bounds);
    k_wcvt<<<20, 256, 0, stream>>>(cW1, cW2, whi, wlo);

    const int AB = (N_NODES * 16 + 255) / 256;
    const int MG = (NTILES + 3) / 4;         // 1563 blocks, 1 tile/wave

    const float* P = x0;
    float* Q = bufA;
    float* spare = bufB;
    for (int l = 0; l < NLAYERS; ++l) {
        const float* sPrev = stats + (size_t)(l - 1) * 128;
        const float* gPrev = gam + (size_t)(l - 1) * 64;
        const float* bPrev = bet + (size_t)(l - 1) * 64;
        const unsigned short* w1h = whi + (size_t)(l * 2) * 4096;
        const unsigned short* w1l = wlo + (size_t)(l * 2) * 4096;
        const unsigned short* w2h = whi + (size_t)(l * 2 + 1) * 4096;
        const unsigned short* w2l = wlo + (size_t)(l * 2 + 1) * 4096;
        if (l == 0) {
            k_agg<false><<<AB, 256, 0, stream>>>((const float4*)P, offs, csr, (float4*)Q,
                                                 nullptr, nullptr, nullptr);
        } else {
            k_agg<true><<<AB, 256, 0, stream>>>((const float4*)P, offs, csr, (float4*)Q,
                                                sPrev, gPrev, bPrev);
        }
        k_mlp5<<<MG, 256, 0, stream>>>(Q, w1h, w1l, w2h, w2l,
                                       cb1 + l * 64, cb2 + l * 64,
                                       stats + (size_t)l * 128);
        float* newSpare = (P == x0) ? spare : (float*)P;
        P = Q;
        Q = newSpare;
    }

    k_pool<<<NGRAPH, 256, 0, stream>>>((const float4*)P, bounds, (float4*)pooled,
                                       stats + 4 * 128, gam + 4 * 64, bet + 4 * 64);
    k_head<<<1, 128, 0, stream>>>(pooled, hW1, hb1, hW2, hb2, out);
}

// Round 9
// 941.743 us; speedup vs baseline: 1.4020x; 1.4020x over previous
//
#include <hip/hip_runtime.h>

#define N_NODES 100000
#define N_EDGES 1600000
#define HDIM    64
#define NLAYERS 5
#define NGRAPH  128
#define NOUT    10
#define BN_EPS  1e-5f
#define NBUCK   196          // ceil(N_NODES / 512)
#define EPB     8192         // edges per binfill block

// ---------------- CSR build ----------------

__global__ __launch_bounds__(256) void k_hist(const int* __restrict__ dst, int* __restrict__ counts) {
    int e = blockIdx.x * 256 + threadIdx.x;
    if (e < N_EDGES) atomicAdd(&counts[dst[e]], 1);
}

__global__ __launch_bounds__(256) void k_scan_bt(const int* __restrict__ counts, int* __restrict__ bsums) {
    __shared__ int sm[256];
    int t = threadIdx.x;
    int base = blockIdx.x * 1024 + t * 4;
    int s = 0;
#pragma unroll
    for (int k = 0; k < 4; ++k) { int i = base + k; s += (i < N_NODES) ? counts[i] : 0; }
    sm[t] = s; __syncthreads();
    for (int o = 128; o > 0; o >>= 1) { if (t < o) sm[t] += sm[t + o]; __syncthreads(); }
    if (t == 0) bsums[blockIdx.x] = sm[0];
}

__global__ void k_scan_tot(int* bsums, int nblk, int* offsets) {
    if (threadIdx.x == 0 && blockIdx.x == 0) {
        int run = 0;
        for (int i = 0; i < nblk; ++i) { int v = bsums[i]; bsums[i] = run; run += v; }
        offsets[N_NODES] = N_EDGES;
    }
}

__global__ __launch_bounds__(256) void k_scan_fin(const int* __restrict__ counts, const int* __restrict__ bsums,
                                                 int* __restrict__ offsets, int* __restrict__ cursor) {
    __shared__ int sm[256];
    int t = threadIdx.x;
    int base = blockIdx.x * 1024 + t * 4;
    int v[4]; int s = 0;
#pragma unroll
    for (int k = 0; k < 4; ++k) { int i = base + k; v[k] = (i < N_NODES) ? counts[i] : 0; s += v[k]; }
    sm[t] = s; __syncthreads();
    for (int o = 1; o < 256; o <<= 1) {
        int add = (t >= o) ? sm[t - o] : 0;
        __syncthreads();
        sm[t] += add;
        __syncthreads();
    }
    int run = bsums[blockIdx.x] + (sm[t] - s);
#pragma unroll
    for (int k = 0; k < 4; ++k) {
        int i = base + k;
        if (i < N_NODES) { offsets[i] = run; cursor[i] = run; run += v[k]; }
    }
}

__global__ void k_binit(const int* __restrict__ offs, int* __restrict__ bcursor) {
    int b = blockIdx.x * 256 + threadIdx.x;
    if (b < NBUCK) bcursor[b] = offs[b << 9];
}

__global__ __launch_bounds__(1024) void k_binfill(const int* __restrict__ src, const int* __restrict__ dst,
                                                  int* __restrict__ bcursor, unsigned* __restrict__ tmp) {
    __shared__ unsigned slots[EPB];
    __shared__ int cnt[NBUCK], lcur[NBUCK], gbase[NBUCK];
    __shared__ int lbase[NBUCK + 1];
    __shared__ int sscan[256];
    int t = threadIdx.x;
    int e0 = blockIdx.x * EPB;
    for (int i = t; i < NBUCK; i += 1024) { cnt[i] = 0; lcur[i] = 0; }
    __syncthreads();
    unsigned pk[8]; int bk[8];
#pragma unroll
    for (int k = 0; k < 8; ++k) {
        int e = e0 + k * 1024 + t;
        bk[k] = -1;
        if (e < N_EDGES) {
            int s = src[e], d = dst[e];
            int b = d >> 9;
            pk[k] = ((unsigned)(d & 511) << 17) | (unsigned)s;
            bk[k] = b;
            atomicAdd(&cnt[b], 1);
        }
    }
    __syncthreads();
    if (t < 256) sscan[t] = (t < NBUCK) ? cnt[t] : 0;
    __syncthreads();
    for (int o = 1; o < 256; o <<= 1) {
        int v = 0;
        if (t < 256 && t >= o) v = sscan[t - o];
        __syncthreads();
        if (t < 256) sscan[t] += v;
        __syncthreads();
    }
    if (t < NBUCK) {
        lbase[t] = sscan[t] - cnt[t];
        gbase[t] = atomicAdd(&bcursor[t], cnt[t]);
    }
    if (t == 0) lbase[NBUCK] = sscan[255];
    __syncthreads();
#pragma unroll
    for (int k = 0; k < 8; ++k) {
        if (bk[k] >= 0) {
            int pos = lbase[bk[k]] + atomicAdd(&lcur[bk[k]], 1);
            slots[pos] = pk[k];
        }
    }
    __syncthreads();
    int total = lbase[NBUCK];
    for (int i = t; i < total; i += 1024) {
        int lo = 0, hi = NBUCK - 1;
        while (lo < hi) { int mid = (lo + hi + 1) >> 1; if (lbase[mid] <= i) lo = mid; else hi = mid - 1; }
        tmp[gbase[lo] + (i - lbase[lo])] = slots[i];
    }
}

__global__ __launch_bounds__(1024) void k_localcsr(const unsigned* __restrict__ tmp, const int* __restrict__ offs,
                                                   int* __restrict__ cursor, int* __restrict__ csr) {
    int b = blockIdx.x;
    int nlo = b << 9;
    int nhi = nlo + 512; if (nhi > N_NODES) nhi = N_NODES;
    int base = offs[nlo], end = offs[nhi];
    for (int i = base + (int)threadIdx.x; i < end; i += 1024) {
        unsigned pk = tmp[i];
        int node = nlo + (int)(pk >> 17);
        int p = atomicAdd(&cursor[node], 1);
        csr[p] = (int)(pk & 0x1FFFFu);
    }
}

// ---------------- per-layer kernels (BN fused into consumers) ----------------

static __device__ __forceinline__ void bn_coeffs(const float* stats, const float* gam, const float* bet,
                                                 int j0, float4& sc, float4& sh) {
    const float invN = 1.0f / (float)N_NODES;
    float m, v, s;
    m = stats[j0+0]*invN; v = stats[64+j0+0]*invN - m*m; s = gam[j0+0]*rsqrtf(v+BN_EPS); sc.x = s; sh.x = bet[j0+0]-m*s;
    m = stats[j0+1]*invN; v = stats[64+j0+1]*invN - m*m; s = gam[j0+1]*rsqrtf(v+BN_EPS); sc.y = s; sh.y = bet[j0+1]-m*s;
    m = stats[j0+2]*invN; v = stats[64+j0+2]*invN - m*m; s = gam[j0+2]*rsqrtf(v+BN_EPS); sc.z = s; sh.z = bet[j0+2]-m*s;
    m = stats[j0+3]*invN; v = stats[64+j0+3]*invN - m*m; s = gam[j0+3]*rsqrtf(v+BN_EPS); sc.w = s; sh.w = bet[j0+3]-m*s;
}

static __device__ __forceinline__ float4 bn_apply(float4 v, const float4& sc, const float4& sh) {
    v.x = fmaxf(fmaf(v.x, sc.x, sh.x), 0.f);
    v.y = fmaxf(fmaf(v.y, sc.y, sh.y), 0.f);
    v.z = fmaxf(fmaf(v.z, sc.z, sh.z), 0.f);
    v.w = fmaxf(fmaf(v.w, sc.w, sh.w), 0.f);
    return v;
}

// 16 lanes per node, float4 per lane. GIN input fused: starts from own row
// (BN'd for layers>0), adds all neighbors -> writes x + sum_neighbors.
template <bool APPLY>
__global__ __launch_bounds__(256) void k_agg(const float4* __restrict__ x4, const int* __restrict__ offsets,
                                             const int* __restrict__ csr, float4* __restrict__ agg4,
                                             const float* __restrict__ stats, const float* __restrict__ gam,
                                             const float* __restrict__ bet) {
    int tid = blockIdx.x * 256 + threadIdx.x;
    int n = tid >> 4, q = tid & 15;
    if (n >= N_NODES) return;
    float4 sc, sh;
    if (APPLY) bn_coeffs(stats, gam, bet, q * 4, sc, sh);
    int beg = offsets[n], end = offsets[n + 1];
    float4 a0 = x4[(size_t)n * 16 + q];          // self term (eps=0)
    if (APPLY) a0 = bn_apply(a0, sc, sh);
    float4 a1 = make_float4(0.f, 0.f, 0.f, 0.f);
    int e = beg;
    for (; e + 1 < end; e += 2) {
        int s0 = csr[e], s1 = csr[e + 1];
        float4 v0 = x4[(size_t)s0 * 16 + q];
        float4 v1 = x4[(size_t)s1 * 16 + q];
        if (APPLY) { v0 = bn_apply(v0, sc, sh); v1 = bn_apply(v1, sc, sh); }
        a0.x += v0.x; a0.y += v0.y; a0.z += v0.z; a0.w += v0.w;
        a1.x += v1.x; a1.y += v1.y; a1.z += v1.z; a1.w += v1.w;
    }
    if (e < end) {
        int s0 = csr[e];
        float4 v0 = x4[(size_t)s0 * 16 + q];
        if (APPLY) v0 = bn_apply(v0, sc, sh);
        a0.x += v0.x; a0.y += v0.y; a0.z += v0.z; a0.w += v0.w;
    }
    a0.x += a1.x; a0.y += a1.y; a0.z += a1.z; a0.w += a1.w;
    agg4[(size_t)n * 16 + q] = a0;
}

// thread = node. Input row (= x + agg, fused upstream) staged in LDS.
// Weights via wave-uniform scalar loads; j-SPLIT k-loops keep the per-pass
// weight working set at 8 KB so it stays K$-resident (the 83us version
// thrashed K$ with 16+16 KB alternating sweeps). Writes h2 in-place and
// accumulates BN stats.
#define MLP_TB 128
#define ROWS   68
__global__ __launch_bounds__(MLP_TB) void k_mlp6(float* __restrict__ aggh2,
                                                 const float* __restrict__ W1, const float* __restrict__ b1,
                                                 const float* __restrict__ W2, const float* __restrict__ b2,
                                                 float* __restrict__ statsOut) {
    __shared__ float sm[MLP_TB * ROWS];
    __shared__ float red1[MLP_TB], red2[MLP_TB];
    int t = threadIdx.x;
    int base = blockIdx.x * MLP_TB;
    for (int i = t; i < MLP_TB * 16; i += MLP_TB) {
        int r = i >> 4, q = i & 15;
        int n = base + r; if (n >= N_NODES) n = N_NODES - 1;
        float4 av = ((const float4*)aggh2)[(size_t)n * 16 + q];
        *((float4*)&sm[r * ROWS + q * 4]) = av;
    }
    __syncthreads();
    int n = base + t;
    bool valid = n < N_NODES;
    float* row = &sm[t * ROWS];
    float acc[64];
#pragma unroll
    for (int j = 0; j < 64; ++j) acc[j] = b1[j];
#pragma unroll 1
    for (int jh = 0; jh < 2; ++jh) {           // j-half passes: 8 KB K$ working set
        for (int k = 0; k < 64; ++k) {
            float xk = row[k];
            const float* w = &W1[k * 64 + jh * 32];
#pragma unroll
            for (int j = 0; j < 32; ++j) acc[jh * 32 + j] = fmaf(xk, w[j], acc[jh * 32 + j]);
        }
    }
#pragma unroll
    for (int q = 0; q < 16; ++q) {
        float4 h;
        h.x = fmaxf(acc[4 * q + 0], 0.f);
        h.y = fmaxf(acc[4 * q + 1], 0.f);
        h.z = fmaxf(acc[4 * q + 2], 0.f);
        h.w = fmaxf(acc[4 * q + 3], 0.f);
        *((float4*)&row[q * 4]) = h;   // own row only: no barrier needed
    }
#pragma unroll
    for (int j = 0; j < 64; ++j) acc[j] = b2[j];
#pragma unroll 1
    for (int jh = 0; jh < 2; ++jh) {
        for (int k = 0; k < 64; ++k) {
            float xk = row[k];
            const float* w = &W2[k * 64 + jh * 32];
#pragma unroll
            for (int j = 0; j < 32; ++j) acc[jh * 32 + j] = fmaf(xk, w[j], acc[jh * 32 + j]);
        }
    }
    if (valid) {
        float4* o = (float4*)(aggh2 + (size_t)n * 64);
#pragma unroll
        for (int q = 0; q < 16; ++q)
            o[q] = make_float4(acc[4 * q + 0], acc[4 * q + 1], acc[4 * q + 2], acc[4 * q + 3]);
    }
    // ---- fused BN statistics (zeros for padding rows keep sums exact) ----
#pragma unroll
    for (int q = 0; q < 16; ++q) {
        float4 h;
        if (valid) h = make_float4(acc[4*q+0], acc[4*q+1], acc[4*q+2], acc[4*q+3]);
        else       h = make_float4(0.f, 0.f, 0.f, 0.f);
        *((float4*)&row[q * 4]) = h;
    }
    __syncthreads();
    {
        int j = t & 63, half = t >> 6;
        float s = 0.f, sq = 0.f;
        const float* col = &sm[(half * 64) * ROWS + j];
#pragma unroll 8
        for (int r = 0; r < 64; ++r) { float v = col[r * ROWS]; s += v; sq += v * v; }
        red1[t] = s; red2[t] = sq;
    }
    __syncthreads();
    if (t < 64) {
        atomicAdd(&statsOut[t], red1[t] + red1[t + 64]);
    } else {
        int j = t - 64;
        atomicAdd(&statsOut[64 + j], red2[j] + red2[j + 64]);
    }
}

// ---------------- pooling + head (b is sorted -> segment boundaries) ----------------

__global__ void k_bounds(const int* __restrict__ b, int* __restrict__ bounds) {
    int g = threadIdx.x;
    if (g > NGRAPH) return;
    int lo = 0, hi = N_NODES;
    while (lo < hi) { int mid = (lo + hi) >> 1; if (b[mid] < g) lo = mid + 1; else hi = mid; }
    bounds[g] = lo;
}

__global__ __launch_bounds__(256) void k_pool(const float4* __restrict__ x4, const int* __restrict__ bounds,
                                              float4* __restrict__ pooled4, const float* __restrict__ stats,
                                              const float* __restrict__ gam, const float* __restrict__ bet) {
    int g = blockIdx.x;
    int beg = bounds[g], end = bounds[g + 1];
    int t = threadIdx.x;
    int q = t & 15;
    int w = t >> 4;
    float4 sc, sh;
    bn_coeffs(stats, gam, bet, q * 4, sc, sh);
    float4 a = make_float4(0.f, 0.f, 0.f, 0.f);
    for (int n = beg + w; n < end; n += 16) {
        float4 v = bn_apply(x4[(size_t)n * 16 + q], sc, sh);
        a.x += v.x; a.y += v.y; a.z += v.z; a.w += v.w;
    }
    __shared__ float4 sm[16][16];
    sm[w][q] = a; __syncthreads();
    for (int o = 8; o > 0; o >>= 1) {
        if (w < o) {
            float4 u = sm[w + o][q];
            sm[w][q].x += u.x; sm[w][q].y += u.y; sm[w][q].z += u.z; sm[w][q].w += u.w;
        }
        __syncthreads();
    }
    if (w == 0) {
        float inv = (end > beg) ? 1.0f / (float)(end - beg) : 0.0f;
        float4 r = sm[0][q];
        r.x *= inv; r.y *= inv; r.z *= inv; r.w *= inv;
        pooled4[g * 16 + q] = r;
    }
}

__global__ __launch_bounds__(128) void k_head(const float* __restrict__ pooled,
                                              const float* __restrict__ W1, const float* __restrict__ b1,
                                              const float* __restrict__ W2, const float* __restrict__ b2,
                                              float* __restrict__ out) {
    __shared__ float w1s[64 * 64];
    __shared__ float w2s[64 * NOUT];
    int t = threadIdx.x;
    for (int i = t; i < 64 * 64; i += 128) w1s[i] = W1[i];
    for (int i = t; i < 64 * NOUT; i += 128) w2s[i] = W2[i];
    __syncthreads();
    int g = t;
    float pr[64];
#pragma unroll
    for (int k = 0; k < 64; ++k) pr[k] = pooled[g * 64 + k];
    float acc[NOUT];
#pragma unroll
    for (int o = 0; o < NOUT; ++o) acc[o] = b2[o];
    for (int j = 0; j < 64; ++j) {
        float h = b1[j];
#pragma unroll
        for (int k = 0; k < 64; ++k) h = fmaf(pr[k], w1s[k * 64 + j], h);
        h = fmaxf(h, 0.f);
#pragma unroll
        for (int o = 0; o < NOUT; ++o) acc[o] = fmaf(h, w2s[j * NOUT + o], acc[o]);
    }
#pragma unroll
    for (int o = 0; o < NOUT; ++o) out[g * NOUT + o] = acc[o];
}

// ---------------- launch ----------------

extern "C" void kernel_launch(void* const* d_in, const int* in_sizes, int n_in,
                              void* d_out, int out_size, void* d_ws, size_t ws_size,
                              hipStream_t stream) {
    const float* x0  = (const float*)d_in[0];
    const int*   ei  = (const int*)d_in[1];
    const int*   b   = (const int*)d_in[2];
    const float* cW1 = (const float*)d_in[3];
    const float* cb1 = (const float*)d_in[4];
    const float* cW2 = (const float*)d_in[5];
    const float* cb2 = (const float*)d_in[6];
    const float* gam = (const float*)d_in[7];
    const float* bet = (const float*)d_in[8];
    const float* hW1 = (const float*)d_in[9];
    const float* hb1 = (const float*)d_in[10];
    const float* hW2 = (const float*)d_in[11];
    const float* hb2 = (const float*)d_in[12];
    float* out = (float*)d_out;

    char* ws = (char*)d_ws;
    size_t off = 0;
    auto alloc = [&](size_t bytes) { void* p = ws + off; off += (bytes + 255) & ~(size_t)255; return p; };
    float* bufA   = (float*)alloc((size_t)N_NODES * 64 * sizeof(float));
    float* bufB   = (float*)alloc((size_t)N_NODES * 64 * sizeof(float));
    int*   csr    = (int*)alloc((size_t)N_EDGES * sizeof(int));
    int*   counts = (int*)alloc((size_t)(N_NODES + 1) * sizeof(int));
    int*   offs   = (int*)alloc((size_t)(N_NODES + 1) * sizeof(int));
    int*   cursor = (int*)alloc((size_t)(N_NODES + 1) * sizeof(int));
    int*   bsums  = (int*)alloc(256 * sizeof(int));
    int*   bcursor= (int*)alloc(256 * sizeof(int));
    float* stats  = (float*)alloc(NLAYERS * 128 * sizeof(float));
    float* pooled = (float*)alloc(NGRAPH * 64 * sizeof(float));
    int*   bounds = (int*)alloc((NGRAPH + 1) * sizeof(int));
    unsigned* tmp = (unsigned*)bufB;   // alias: bufB unused until layer 1

    const int* src = ei;
    const int* dst = ei + N_EDGES;

    hipMemsetAsync(counts, 0, (N_NODES + 1) * sizeof(int), stream);
    hipMemsetAsync(stats, 0, NLAYERS * 128 * sizeof(float), stream);

    const int EB = (N_EDGES + 255) / 256;
    const int SB = (N_NODES + 1023) / 1024;
    const int FB = (N_EDGES + EPB - 1) / EPB;
    k_hist<<<EB, 256, 0, stream>>>(dst, counts);
    k_scan_bt<<<SB, 256, 0, stream>>>(counts, bsums);
    k_scan_tot<<<1, 1, 0, stream>>>(bsums, SB, offs);
    k_scan_fin<<<SB, 256, 0, stream>>>(counts, bsums, offs, cursor);
    k_binit<<<1, 256, 0, stream>>>(offs, bcursor);
    k_binfill<<<FB, 1024, 0, stream>>>(src, dst, bcursor, tmp);
    k_localcsr<<<NBUCK, 1024, 0, stream>>>(tmp, offs, cursor, csr);
    k_bounds<<<1, NGRAPH + 1, 0, stream>>>(b, bounds);

    const int AB = (N_NODES * 16 + 255) / 256;
    const int MB_G = (N_NODES + MLP_TB - 1) / MLP_TB;

    const float* P = x0;
    float* Q = bufA;
    float* spare = bufB;
    for (int l = 0; l < NLAYERS; ++l) {
        const float* sPrev = stats + (size_t)(l - 1) * 128;
        const float* gPrev = gam + (size_t)(l - 1) * 64;
        const float* bPrev = bet + (size_t)(l - 1) * 64;
        if (l == 0) {
            k_agg<false><<<AB, 256, 0, stream>>>((const float4*)P, offs, csr, (float4*)Q,
                                                 nullptr, nullptr, nullptr);
        } else {
            k_agg<true><<<AB, 256, 0, stream>>>((const float4*)P, offs, csr, (float4*)Q,
                                                sPrev, gPrev, bPrev);
        }
        k_mlp6<<<MB_G, MLP_TB, 0, stream>>>(Q,
                                            cW1 + (size_t)l * 64 * 64, cb1 + l * 64,
                                            cW2 + (size_t)l * 64 * 64, cb2 + l * 64,
                                            stats + (size_t)l * 128);
        float* newSpare = (P == x0) ? spare : (float*)P;
        P = Q;
        Q = newSpare;
    }

    k_pool<<<NGRAPH, 256, 0, stream>>>((const float4*)P, bounds, (float4*)pooled,
                                       stats + 4 * 128, gam + 4 * 64, bet + 4 * 64);
    k_head<<<1, 128, 0, stream>>>(pooled, hW1, hb1, hW2, hb2, out);
}

// Round 10
// 855.627 us; speedup vs baseline: 1.5431x; 1.1006x over previous
//
#include <hip/hip_runtime.h>

#define N_NODES 100000
#define N_EDGES 1600000
#define HDIM    64
#define NLAYERS 5
#define NGRAPH  128
#define NOUT    10
#define BN_EPS  1e-5f
#define NBUCK   196          // ceil(N_NODES / 512)
#define EPB     8192         // edges per binfill block

// ---------------- CSR build ----------------

__global__ __launch_bounds__(256) void k_hist(const int* __restrict__ dst, int* __restrict__ counts) {
    int e = blockIdx.x * 256 + threadIdx.x;
    if (e < N_EDGES) atomicAdd(&counts[dst[e]], 1);
}

__global__ __launch_bounds__(256) void k_scan_bt(const int* __restrict__ counts, int* __restrict__ bsums) {
    __shared__ int sm[256];
    int t = threadIdx.x;
    int base = blockIdx.x * 1024 + t * 4;
    int s = 0;
#pragma unroll
    for (int k = 0; k < 4; ++k) { int i = base + k; s += (i < N_NODES) ? counts[i] : 0; }
    sm[t] = s; __syncthreads();
    for (int o = 128; o > 0; o >>= 1) { if (t < o) sm[t] += sm[t + o]; __syncthreads(); }
    if (t == 0) bsums[blockIdx.x] = sm[0];
}

__global__ void k_scan_tot(int* bsums, int nblk, int* offsets) {
    if (threadIdx.x == 0 && blockIdx.x == 0) {
        int run = 0;
        for (int i = 0; i < nblk; ++i) { int v = bsums[i]; bsums[i] = run; run += v; }
        offsets[N_NODES] = N_EDGES;
    }
}

__global__ __launch_bounds__(256) void k_scan_fin(const int* __restrict__ counts, const int* __restrict__ bsums,
                                                 int* __restrict__ offsets, int* __restrict__ cursor) {
    __shared__ int sm[256];
    int t = threadIdx.x;
    int base = blockIdx.x * 1024 + t * 4;
    int v[4]; int s = 0;
#pragma unroll
    for (int k = 0; k < 4; ++k) { int i = base + k; v[k] = (i < N_NODES) ? counts[i] : 0; s += v[k]; }
    sm[t] = s; __syncthreads();
    for (int o = 1; o < 256; o <<= 1) {
        int add = (t >= o) ? sm[t - o] : 0;
        __syncthreads();
        sm[t] += add;
        __syncthreads();
    }
    int run = bsums[blockIdx.x] + (sm[t] - s);
#pragma unroll
    for (int k = 0; k < 4; ++k) {
        int i = base + k;
        if (i < N_NODES) { offsets[i] = run; cursor[i] = run; run += v[k]; }
    }
}

__global__ void k_binit(const int* __restrict__ offs, int* __restrict__ bcursor) {
    int b = blockIdx.x * 256 + threadIdx.x;
    if (b < NBUCK) bcursor[b] = offs[b << 9];
}

__global__ __launch_bounds__(1024) void k_binfill(const int* __restrict__ src, const int* __restrict__ dst,
                                                  int* __restrict__ bcursor, unsigned* __restrict__ tmp) {
    __shared__ unsigned slots[EPB];
    __shared__ int cnt[NBUCK], lcur[NBUCK], gbase[NBUCK];
    __shared__ int lbase[NBUCK + 1];
    __shared__ int sscan[256];
    int t = threadIdx.x;
    int e0 = blockIdx.x * EPB;
    for (int i = t; i < NBUCK; i += 1024) { cnt[i] = 0; lcur[i] = 0; }
    __syncthreads();
    unsigned pk[8]; int bk[8];
#pragma unroll
    for (int k = 0; k < 8; ++k) {
        int e = e0 + k * 1024 + t;
        bk[k] = -1;
        if (e < N_EDGES) {
            int s = src[e], d = dst[e];
            int b = d >> 9;
            pk[k] = ((unsigned)(d & 511) << 17) | (unsigned)s;
            bk[k] = b;
            atomicAdd(&cnt[b], 1);
        }
    }
    __syncthreads();
    if (t < 256) sscan[t] = (t < NBUCK) ? cnt[t] : 0;
    __syncthreads();
    for (int o = 1; o < 256; o <<= 1) {
        int v = 0;
        if (t < 256 && t >= o) v = sscan[t - o];
        __syncthreads();
        if (t < 256) sscan[t] += v;
        __syncthreads();
    }
    if (t < NBUCK) {
        lbase[t] = sscan[t] - cnt[t];
        gbase[t] = atomicAdd(&bcursor[t], cnt[t]);
    }
    if (t == 0) lbase[NBUCK] = sscan[255];
    __syncthreads();
#pragma unroll
    for (int k = 0; k < 8; ++k) {
        if (bk[k] >= 0) {
            int pos = lbase[bk[k]] + atomicAdd(&lcur[bk[k]], 1);
            slots[pos] = pk[k];
        }
    }
    __syncthreads();
    int total = lbase[NBUCK];
    for (int i = t; i < total; i += 1024) {
        int lo = 0, hi = NBUCK - 1;
        while (lo < hi) { int mid = (lo + hi + 1) >> 1; if (lbase[mid] <= i) lo = mid; else hi = mid - 1; }
        tmp[gbase[lo] + (i - lbase[lo])] = slots[i];
    }
}

__global__ __launch_bounds__(1024) void k_localcsr(const unsigned* __restrict__ tmp, const int* __restrict__ offs,
                                                   int* __restrict__ cursor, int* __restrict__ csr) {
    int b = blockIdx.x;
    int nlo = b << 9;
    int nhi = nlo + 512; if (nhi > N_NODES) nhi = N_NODES;
    int base = offs[nlo], end = offs[nhi];
    for (int i = base + (int)threadIdx.x; i < end; i += 1024) {
        unsigned pk = tmp[i];
        int node = nlo + (int)(pk >> 17);
        int p = atomicAdd(&cursor[node], 1);
        csr[p] = (int)(pk & 0x1FFFFu);
    }
}

// ---------------- per-layer kernels (BN fused into consumers) ----------------

static __device__ __forceinline__ void bn_coeffs(const float* stats, const float* gam, const float* bet,
                                                 int j0, float4& sc, float4& sh) {
    const float invN = 1.0f / (float)N_NODES;
    float m, v, s;
    m = stats[j0+0]*invN; v = stats[64+j0+0]*invN - m*m; s = gam[j0+0]*rsqrtf(v+BN_EPS); sc.x = s; sh.x = bet[j0+0]-m*s;
    m = stats[j0+1]*invN; v = stats[64+j0+1]*invN - m*m; s = gam[j0+1]*rsqrtf(v+BN_EPS); sc.y = s; sh.y = bet[j0+1]-m*s;
    m = stats[j0+2]*invN; v = stats[64+j0+2]*invN - m*m; s = gam[j0+2]*rsqrtf(v+BN_EPS); sc.z = s; sh.z = bet[j0+2]-m*s;
    m = stats[j0+3]*invN; v = stats[64+j0+3]*invN - m*m; s = gam[j0+3]*rsqrtf(v+BN_EPS); sc.w = s; sh.w = bet[j0+3]-m*s;
}

static __device__ __forceinline__ float4 bn_apply(float4 v, const float4& sc, const float4& sh) {
    v.x = fmaxf(fmaf(v.x, sc.x, sh.x), 0.f);
    v.y = fmaxf(fmaf(v.y, sc.y, sh.y), 0.f);
    v.z = fmaxf(fmaf(v.z, sc.z, sh.z), 0.f);
    v.w = fmaxf(fmaf(v.w, sc.w, sh.w), 0.f);
    return v;
}

// 16 lanes per node, float4 per lane. GIN input fused: starts from own row
// (BN'd for layers>0), adds all neighbors -> writes x + sum_neighbors.
template <bool APPLY>
__global__ __launch_bounds__(256) void k_agg(const float4* __restrict__ x4, const int* __restrict__ offsets,
                                             const int* __restrict__ csr, float4* __restrict__ agg4,
                                             const float* __restrict__ stats, const float* __restrict__ gam,
                                             const float* __restrict__ bet) {
    int tid = blockIdx.x * 256 + threadIdx.x;
    int n = tid >> 4, q = tid & 15;
    if (n >= N_NODES) return;
    float4 sc, sh;
    if (APPLY) bn_coeffs(stats, gam, bet, q * 4, sc, sh);
    int beg = offsets[n], end = offsets[n + 1];
    float4 a0 = x4[(size_t)n * 16 + q];          // self term (eps=0)
    if (APPLY) a0 = bn_apply(a0, sc, sh);
    float4 a1 = make_float4(0.f, 0.f, 0.f, 0.f);
    int e = beg;
    for (; e + 1 < end; e += 2) {
        int s0 = csr[e], s1 = csr[e + 1];
        float4 v0 = x4[(size_t)s0 * 16 + q];
        float4 v1 = x4[(size_t)s1 * 16 + q];
        if (APPLY) { v0 = bn_apply(v0, sc, sh); v1 = bn_apply(v1, sc, sh); }
        a0.x += v0.x; a0.y += v0.y; a0.z += v0.z; a0.w += v0.w;
        a1.x += v1.x; a1.y += v1.y; a1.z += v1.z; a1.w += v1.w;
    }
    if (e < end) {
        int s0 = csr[e];
        float4 v0 = x4[(size_t)s0 * 16 + q];
        if (APPLY) v0 = bn_apply(v0, sc, sh);
        a0.x += v0.x; a0.y += v0.y; a0.z += v0.z; a0.w += v0.w;
    }
    a0.x += a1.x; a0.y += a1.y; a0.z += a1.z; a0.w += a1.w;
    agg4[(size_t)n * 16 + q] = a0;
}

// thread = node. Input row (= x + agg, fused upstream) staged in LDS.
// Weights via wave-uniform scalar loads. j-split as TWO STATICALLY-INDEXED
// passes (rule: no runtime-indexed register arrays) -> 8 KB weight working
// set per pass stays scalar-cache resident. Writes h2 in-place + BN stats.
#define MLP_TB 128
#define ROWS   68
__global__ __launch_bounds__(MLP_TB) void k_mlp7(float* __restrict__ aggh2,
                                                 const float* __restrict__ W1, const float* __restrict__ b1,
                                                 const float* __restrict__ W2, const float* __restrict__ b2,
                                                 float* __restrict__ statsOut) {
    __shared__ float sm[MLP_TB * ROWS];
    __shared__ float red1[MLP_TB], red2[MLP_TB];
    int t = threadIdx.x;
    int base = blockIdx.x * MLP_TB;
    for (int i = t; i < MLP_TB * 16; i += MLP_TB) {
        int r = i >> 4, q = i & 15;
        int n = base + r; if (n >= N_NODES) n = N_NODES - 1;
        float4 av = ((const float4*)aggh2)[(size_t)n * 16 + q];
        *((float4*)&sm[r * ROWS + q * 4]) = av;
    }
    __syncthreads();
    int n = base + t;
    bool valid = n < N_NODES;
    float* row = &sm[t * ROWS];
    float acc[64];
#pragma unroll
    for (int j = 0; j < 64; ++j) acc[j] = b1[j];
    // ---- GEMM1, j in [0,32): 8 KB weight stream ----
    for (int k = 0; k < 64; ++k) {
        float xk = row[k];
        const float* w = &W1[k * 64];
#pragma unroll
        for (int j = 0; j < 32; ++j) acc[j] = fmaf(xk, w[j], acc[j]);
    }
    // ---- GEMM1, j in [32,64) ----
    for (int k = 0; k < 64; ++k) {
        float xk = row[k];
        const float* w = &W1[k * 64 + 32];
#pragma unroll
        for (int j = 0; j < 32; ++j) acc[32 + j] = fmaf(xk, w[j], acc[32 + j]);
    }
#pragma unroll
    for (int q = 0; q < 16; ++q) {
        float4 h;
        h.x = fmaxf(acc[4 * q + 0], 0.f);
        h.y = fmaxf(acc[4 * q + 1], 0.f);
        h.z = fmaxf(acc[4 * q + 2], 0.f);
        h.w = fmaxf(acc[4 * q + 3], 0.f);
        *((float4*)&row[q * 4]) = h;   // own row only: no barrier needed
    }
#pragma unroll
    for (int j = 0; j < 64; ++j) acc[j] = b2[j];
    // ---- GEMM2, j in [0,32) ----
    for (int k = 0; k < 64; ++k) {
        float xk = row[k];
        const float* w = &W2[k * 64];
#pragma unroll
        for (int j = 0; j < 32; ++j) acc[j] = fmaf(xk, w[j], acc[j]);
    }
    // ---- GEMM2, j in [32,64) ----
    for (int k = 0; k < 64; ++k) {
        float xk = row[k];
        const float* w = &W2[k * 64 + 32];
#pragma unroll
        for (int j = 0; j < 32; ++j) acc[32 + j] = fmaf(xk, w[j], acc[32 + j]);
    }
    if (valid) {
        float4* o = (float4*)(aggh2 + (size_t)n * 64);
#pragma unroll
        for (int q = 0; q < 16; ++q)
            o[q] = make_float4(acc[4 * q + 0], acc[4 * q + 1], acc[4 * q + 2], acc[4 * q + 3]);
    }
    // ---- fused BN statistics (zeros for padding rows keep sums exact) ----
#pragma unroll
    for (int q = 0; q < 16; ++q) {
        float4 h;
        if (valid) h = make_float4(acc[4*q+0], acc[4*q+1], acc[4*q+2], acc[4*q+3]);
        else       h = make_float4(0.f, 0.f, 0.f, 0.f);
        *((float4*)&row[q * 4]) = h;
    }
    __syncthreads();
    {
        int j = t & 63, half = t >> 6;
        float s = 0.f, sq = 0.f;
        const float* col = &sm[(half * 64) * ROWS + j];
#pragma unroll 8
        for (int r = 0; r < 64; ++r) { float v = col[r * ROWS]; s += v; sq += v * v; }
        red1[t] = s; red2[t] = sq;
    }
    __syncthreads();
    if (t < 64) {
        atomicAdd(&statsOut[t], red1[t] + red1[t + 64]);
    } else {
        int j = t - 64;
        atomicAdd(&statsOut[64 + j], red2[j] + red2[j + 64]);
    }
}

// ---------------- pooling + head (b is sorted -> segment boundaries) ----------------

__global__ void k_bounds(const int* __restrict__ b, int* __restrict__ bounds) {
    int g = threadIdx.x;
    if (g > NGRAPH) return;
    int lo = 0, hi = N_NODES;
    while (lo < hi) { int mid = (lo + hi) >> 1; if (b[mid] < g) lo = mid + 1; else hi = mid; }
    bounds[g] = lo;
}

__global__ __launch_bounds__(256) void k_pool(const float4* __restrict__ x4, const int* __restrict__ bounds,
                                              float4* __restrict__ pooled4, const float* __restrict__ stats,
                                              const float* __restrict__ gam, const float* __restrict__ bet) {
    int g = blockIdx.x;
    int beg = bounds[g], end = bounds[g + 1];
    int t = threadIdx.x;
    int q = t & 15;
    int w = t >> 4;
    float4 sc, sh;
    bn_coeffs(stats, gam, bet, q * 4, sc, sh);
    float4 a = make_float4(0.f, 0.f, 0.f, 0.f);
    for (int n = beg + w; n < end; n += 16) {
        float4 v = bn_apply(x4[(size_t)n * 16 + q], sc, sh);
        a.x += v.x; a.y += v.y; a.z += v.z; a.w += v.w;
    }
    __shared__ float4 sm[16][16];
    sm[w][q] = a; __syncthreads();
    for (int o = 8; o > 0; o >>= 1) {
        if (w < o) {
            float4 u = sm[w + o][q];
            sm[w][q].x += u.x; sm[w][q].y += u.y; sm[w][q].z += u.z; sm[w][q].w += u.w;
        }
        __syncthreads();
    }
    if (w == 0) {
        float inv = (end > beg) ? 1.0f / (float)(end - beg) : 0.0f;
        float4 r = sm[0][q];
        r.x *= inv; r.y *= inv; r.z *= inv; r.w *= inv;
        pooled4[g * 16 + q] = r;
    }
}

__global__ __launch_bounds__(128) void k_head(const float* __restrict__ pooled,
                                              const float* __restrict__ W1, const float* __restrict__ b1,
                                              const float* __restrict__ W2, const float* __restrict__ b2,
                                              float* __restrict__ out) {
    __shared__ float w1s[64 * 64];
    __shared__ float w2s[64 * NOUT];
    int t = threadIdx.x;
    for (int i = t; i < 64 * 64; i += 128) w1s[i] = W1[i];
    for (int i = t; i < 64 * NOUT; i += 128) w2s[i] = W2[i];
    __syncthreads();
    int g = t;
    float pr[64];
#pragma unroll
    for (int k = 0; k < 64; ++k) pr[k] = pooled[g * 64 + k];
    float acc[NOUT];
#pragma unroll
    for (int o = 0; o < NOUT; ++o) acc[o] = b2[o];
    for (int j = 0; j < 64; ++j) {
        float h = b1[j];
#pragma unroll
        for (int k = 0; k < 64; ++k) h = fmaf(pr[k], w1s[k * 64 + j], h);
        h = fmaxf(h, 0.f);
#pragma unroll
        for (int o = 0; o < NOUT; ++o) acc[o] = fmaf(h, w2s[j * NOUT + o], acc[o]);
    }
#pragma unroll
    for (int o = 0; o < NOUT; ++o) out[g * NOUT + o] = acc[o];
}

// ---------------- launch ----------------

extern "C" void kernel_launch(void* const* d_in, const int* in_sizes, int n_in,
                              void* d_out, int out_size, void* d_ws, size_t ws_size,
                              hipStream_t stream) {
    const float* x0  = (const float*)d_in[0];
    const int*   ei  = (const int*)d_in[1];
    const int*   b   = (const int*)d_in[2];
    const float* cW1 = (const float*)d_in[3];
    const float* cb1 = (const float*)d_in[4];
    const float* cW2 = (const float*)d_in[5];
    const float* cb2 = (const float*)d_in[6];
    const float* gam = (const float*)d_in[7];
    const float* bet = (const float*)d_in[8];
    const float* hW1 = (const float*)d_in[9];
    const float* hb1 = (const float*)d_in[10];
    const float* hW2 = (const float*)d_in[11];
    const float* hb2 = (const float*)d_in[12];
    float* out = (float*)d_out;

    char* ws = (char*)d_ws;
    size_t off = 0;
    auto alloc = [&](size_t bytes) { void* p = ws + off; off += (bytes + 255) & ~(size_t)255; return p; };
    float* bufA   = (float*)alloc((size_t)N_NODES * 64 * sizeof(float));
    float* bufB   = (float*)alloc((size_t)N_NODES * 64 * sizeof(float));
    int*   csr    = (int*)alloc((size_t)N_EDGES * sizeof(int));
    int*   counts = (int*)alloc((size_t)(N_NODES + 1) * sizeof(int));
    int*   offs   = (int*)alloc((size_t)(N_NODES + 1) * sizeof(int));
    int*   cursor = (int*)alloc((size_t)(N_NODES + 1) * sizeof(int));
    int*   bsums  = (int*)alloc(256 * sizeof(int));
    int*   bcursor= (int*)alloc(256 * sizeof(int));
    float* stats  = (float*)alloc(NLAYERS * 128 * sizeof(float));
    float* pooled = (float*)alloc(NGRAPH * 64 * sizeof(float));
    int*   bounds = (int*)alloc((NGRAPH + 1) * sizeof(int));
    unsigned* tmp = (unsigned*)bufB;   // alias: bufB unused until layer 1

    const int* src = ei;
    const int* dst = ei + N_EDGES;

    hipMemsetAsync(counts, 0, (N_NODES + 1) * sizeof(int), stream);
    hipMemsetAsync(stats, 0, NLAYERS * 128 * sizeof(float), stream);

    const int EB = (N_EDGES + 255) / 256;
    const int SB = (N_NODES + 1023) / 1024;
    const int FB = (N_EDGES + EPB - 1) / EPB;
    k_hist<<<EB, 256, 0, stream>>>(dst, counts);
    k_scan_bt<<<SB, 256, 0, stream>>>(counts, bsums);
    k_scan_tot<<<1, 1, 0, stream>>>(bsums, SB, offs);
    k_scan_fin<<<SB, 256, 0, stream>>>(counts, bsums, offs, cursor);
    k_binit<<<1, 256, 0, stream>>>(offs, bcursor);
    k_binfill<<<FB, 1024, 0, stream>>>(src, dst, bcursor, tmp);
    k_localcsr<<<NBUCK, 1024, 0, stream>>>(tmp, offs, cursor, csr);
    k_bounds<<<1, NGRAPH + 1, 0, stream>>>(b, bounds);

    const int AB = (N_NODES * 16 + 255) / 256;
    const int MB_G = (N_NODES + MLP_TB - 1) / MLP_TB;

    const float* P = x0;
    float* Q = bufA;
    float* spare = bufB;
    for (int l = 0; l < NLAYERS; ++l) {
        const float* sPrev = stats + (size_t)(l - 1) * 128;
        const float* gPrev = gam + (size_t)(l - 1) * 64;
        const float* bPrev = bet + (size_t)(l - 1) * 64;
        if (l == 0) {
            k_agg<false><<<AB, 256, 0, stream>>>((const float4*)P, offs, csr, (float4*)Q,
                                                 nullptr, nullptr, nullptr);
        } else {
            k_agg<true><<<AB, 256, 0, stream>>>((const float4*)P, offs, csr, (float4*)Q,
                                                sPrev, gPrev, bPrev);
        }
        k_mlp7<<<MB_G, MLP_TB, 0, stream>>>(Q,
                                            cW1 + (size_t)l * 64 * 64, cb1 + l * 64,
                                            cW2 + (size_t)l * 64 * 64, cb2 + l * 64,
                                            stats + (size_t)l * 128);
        float* newSpare = (P == x0) ? spare : (float*)P;
        P = Q;
        Q = newSpare;
    }

    k_pool<<<NGRAPH, 256, 0, stream>>>((const float4*)P, bounds, (float4*)pooled,
                                       stats + 4 * 128, gam + 4 * 64, bet + 4 * 64);
    k_head<<<1, 128, 0, stream>>>(pooled, hW1, hb1, hW2, hb2, out);
}